// Round 19
// baseline (291.003 us; speedup 1.0000x reference)
//
#include <hip/hip_runtime.h>
#include <hip/hip_bf16.h>

#define N_NODES 4096
#define N_EDGES 131072
#define N_GRAPHS 16
#define F_IN 128
#define D 128
#define QKVLD 1536   // 4 modules * 384
#define KSPL 2
#define CHUNK 64
#define NT (2048 / CHUNK)   // chunks per K-split half

typedef __hip_bfloat16 bf16;
typedef __attribute__((ext_vector_type(4))) float f32x4;
typedef __attribute__((ext_vector_type(8))) short bf16x8;

// float -> bf16 bits (RNE)
__device__ __forceinline__ short f2bf(float f) {
    unsigned u = __float_as_uint(f);
    unsigned r = (u + 0x7fffu + ((u >> 16) & 1u)) >> 16;
    return (short)r;
}
__device__ __forceinline__ float bf2f(short b) {
    return __uint_as_float(((unsigned)(unsigned short)b) << 16);
}
// Flagged load: isbf!=0 -> buffer holds bf16, else fp32. i is an ELEMENT index.
__device__ __forceinline__ float ldf(const void* p, long i, int isbf) {
    return isbf ? bf2f(((const short*)p)[i]) : ((const float*)p)[i];
}
// LDS bank swizzles (byte addrs, 16B-alignment preserved): v13-proven (0 conflicts)
__device__ __forceinline__ int swzK(int a) { return a ^ (((a >> 7) & 3) << 4); }
__device__ __forceinline__ int swzV(int a) { return a ^ (((a >> 7) & 7) << 4); }

// ---------------- dtype detector (bf16 data: all halfword exponents < 134) ----------------
__global__ void k_detect(const void* __restrict__ x, int* __restrict__ flag) {
    if (threadIdx.x == 0 && blockIdx.x == 0) {
        const unsigned short* h = (const unsigned short*)x;
        int bf = 1;
        for (int i = 0; i < 64; ++i) {
            int e = (h[i] >> 7) & 0xFF;
            if (e >= 134) { bf = 0; break; }
        }
        *flag = bf;
    }
}

// ---------------- flag-aware conversion of MFMA operand tensors to bf16 ----------------
struct ConvSegs {
    const void* src0; const void* src1; const void* src2; const void* src3; const void* src4;
    short* dst0; short* dst1; short* dst2; short* dst3; short* dst4;
    int e0, e1, e2, e3, e4;
};
__global__ void k_tobf16(ConvSegs s, const int* __restrict__ flag) {
    int idx = blockIdx.x * 256 + threadIdx.x;
    int isbf = *flag;
    const void* src; short* dst; int base;
    if (idx < s.e0)      { src = s.src0; dst = s.dst0; base = 0; }
    else if (idx < s.e1) { src = s.src1; dst = s.dst1; base = s.e0; }
    else if (idx < s.e2) { src = s.src2; dst = s.dst2; base = s.e1; }
    else if (idx < s.e3) { src = s.src3; dst = s.dst3; base = s.e2; }
    else if (idx < s.e4) { src = s.src4; dst = s.dst4; base = s.e3; }
    else return;
    int i = idx - base;
    dst[i] = f2bf(ldf(src, i, isbf));
}

__global__ void k_deg(const int* __restrict__ dst, int* __restrict__ degi) {
    int e = blockIdx.x * 256 + threadIdx.x;
    if (e < N_EDGES) atomicAdd(&degi[dst[e]], 1);
}

// ---------------- fused prep: degree scan + dinv + batch boundaries (one block) ----------------
__global__ __launch_bounds__(1024) void k_prep(const int* __restrict__ degi,
                                               const int* __restrict__ batch,
                                               int* __restrict__ offs,
                                               int* __restrict__ cursor,
                                               float* __restrict__ dinv,
                                               int* __restrict__ starts) {
    __shared__ int part[1024];
    int t = threadIdx.x;
    int4 v = *(const int4*)(degi + t * 4);
    int dv[4] = {v.x, v.y, v.z, v.w};
    int s = dv[0] + dv[1] + dv[2] + dv[3];
    part[t] = s;
    __syncthreads();
    for (int ofs = 1; ofs < 1024; ofs <<= 1) {
        int val = (t >= ofs) ? part[t - ofs] : 0;
        __syncthreads();
        part[t] += val;
        __syncthreads();
    }
    int o = part[t] - s;
#pragma unroll
    for (int j = 0; j < 4; ++j) {
        int n = t * 4 + j;
        offs[n] = o; cursor[n] = o;
        o += dv[j];
        dinv[n] = rsqrtf((float)(dv[j] + 1));   // +1 self loop
    }
    if (t == 1023) offs[4096] = o;
    // batch boundaries (batch is sorted)
#pragma unroll
    for (int j = 0; j < 4; ++j) {
        int n = t * 4 + j;
        int b = batch[n];
        if (n == 0) { for (int g2 = 0; g2 <= b; ++g2) starts[g2] = 0; }
        else {
            int pb = batch[n - 1];
            for (int g2 = pb + 1; g2 <= b; ++g2) starts[g2] = n;
        }
        if (n == N_NODES - 1) { for (int g2 = b + 1; g2 <= N_GRAPHS; ++g2) starts[g2] = N_NODES; }
    }
}

__global__ void k_sortedges(const int* __restrict__ src, const int* __restrict__ dst,
                            int* __restrict__ cursor, int* __restrict__ sSrc) {
    int e = blockIdx.x * 256 + threadIdx.x;
    if (e >= N_EDGES) return;
    int d = dst[e];
    int pos = atomicAdd(&cursor[d], 1);
    sSrc[pos] = src[e];
}

// ---------------- MFMA GEMM v2 (templated K, B-panel in regs, 8 n-tiles/block) ----------------
// C[M][ldc] bf16 = A @ W^T, lda == K at both call sites. grid (cols/16, 32).
template<int K>
__global__ __launch_bounds__(64) void k_mfma_gemm_t(const short* __restrict__ A,
                                                    const short* __restrict__ W,
                                                    short* __restrict__ C, int ldc) {
    const int lane = threadIdx.x;
    const int m15 = lane & 15, quad = lane >> 4;
    const int c0 = blockIdx.x * 16;
    bf16x8 bv[K / 32];
#pragma unroll
    for (int kk = 0; kk < K / 32; ++kk)
        bv[kk] = *(const bf16x8*)(W + (long)(c0 + m15) * K + kk * 32 + quad * 8);
#pragma unroll
    for (int t = 0; t < 8; ++t) {
        const int n0 = blockIdx.y * 128 + t * 16;
        f32x4 acc = {0.f, 0.f, 0.f, 0.f};
#pragma unroll
        for (int kk = 0; kk < K / 32; ++kk) {
            bf16x8 a = *(const bf16x8*)(A + (long)(n0 + m15) * K + kk * 32 + quad * 8);
            acc = __builtin_amdgcn_mfma_f32_16x16x32_bf16(a, bv[kk], acc, 0, 0, 0);
        }
#pragma unroll
        for (int i = 0; i < 4; ++i)
            C[(long)(n0 + quad * 4 + i) * ldc + c0 + m15] = f2bf(acc[i]);
    }
}

// ---------------- fused qkv MFMA v2: B-panel in registers, 8 n-tiles per block ----------------
// grid (96, 32). Each block owns one 16-col output panel (c0) and iterates 8 n-tiles,
// reusing the B-fragments (4x bf16x8 regs) and the hoisted scatter-epilogue constants.
// Measured win: total 293.1 -> 282.9 us vs 1-tile blocks.
__global__ __launch_bounds__(64) void k_qkv(const short* __restrict__ h2b,
                                            const short* __restrict__ Winb,
                                            const void* __restrict__ bin,
                                            const int* __restrict__ flag,
                                            short* __restrict__ Qb,
                                            short* __restrict__ Kb,
                                            short* __restrict__ VTb) {
    const int lane = threadIdx.x;
    const int m15 = lane & 15, quad = lane >> 4;
    const int c0 = blockIdx.x * 16;

    // B-panel once (4 K-fragments of the 16 output cols)
    bf16x8 bv0 = *(const bf16x8*)(Winb + (long)(c0 + m15) * 128 +  0 + quad * 8);
    bf16x8 bv1 = *(const bf16x8*)(Winb + (long)(c0 + m15) * 128 + 32 + quad * 8);
    bf16x8 bv2 = *(const bf16x8*)(Winb + (long)(c0 + m15) * 128 + 64 + quad * 8);
    bf16x8 bv3 = *(const bf16x8*)(Winb + (long)(c0 + m15) * 128 + 96 + quad * 8);

    // scatter-epilogue constants (n-independent), hoisted out of the n-loop
    const int c = c0 + m15;           // D layout: col = lane&15
    const int mmod = c / 384;
    const int r = c - mmod * 384;
    const int sect = r >> 7;          // 0=q, 1=k, 2=v (uniform per block)
    const int rr = r & 127;
    const int head = mmod * 4 + (rr >> 5);
    const int d = rr & 31;
    const float bias = ldf(bin, c, *flag);
    const float scale = 0.17677669529663687f * 1.4426950408889634f;  // 1/sqrt(32)*log2(e)

#pragma unroll
    for (int t = 0; t < 8; ++t) {
        const int n0 = blockIdx.y * 128 + t * 16;
        f32x4 acc = {0.f, 0.f, 0.f, 0.f};
        {
            bf16x8 a0 = *(const bf16x8*)(h2b + (long)(n0 + m15) * 128 +  0 + quad * 8);
            acc = __builtin_amdgcn_mfma_f32_16x16x32_bf16(a0, bv0, acc, 0, 0, 0);
            bf16x8 a1 = *(const bf16x8*)(h2b + (long)(n0 + m15) * 128 + 32 + quad * 8);
            acc = __builtin_amdgcn_mfma_f32_16x16x32_bf16(a1, bv1, acc, 0, 0, 0);
            bf16x8 a2 = *(const bf16x8*)(h2b + (long)(n0 + m15) * 128 + 64 + quad * 8);
            acc = __builtin_amdgcn_mfma_f32_16x16x32_bf16(a2, bv2, acc, 0, 0, 0);
            bf16x8 a3 = *(const bf16x8*)(h2b + (long)(n0 + m15) * 128 + 96 + quad * 8);
            acc = __builtin_amdgcn_mfma_f32_16x16x32_bf16(a3, bv3, acc, 0, 0, 0);
        }
        if (sect == 0) {
#pragma unroll
            for (int i = 0; i < 4; ++i)   // D layout: row = quad*4 + i
                Qb[(long)head * 131072 + (long)(n0 + quad * 4 + i) * 32 + d] = f2bf((acc[i] + bias) * scale);
        } else if (sect == 1) {
#pragma unroll
            for (int i = 0; i < 4; ++i)
                Kb[(long)head * 131072 + (long)(n0 + quad * 4 + i) * 32 + d] = f2bf(acc[i] + bias);
        } else {
            long vbase = (long)head * 131072 + (long)d * 4096;
#pragma unroll
            for (int i = 0; i < 4; ++i) {
                int n = n0 + quad * 4 + i;
                int phys = (n & ~31) | ((((n >> 2) & 3) << 3) | (((n >> 4) & 1) << 2) | (n & 3));
                VTb[vbase + phys] = f2bf(acc[i] + bias);
            }
        }
    }
}

// ---------------- GCN gather (CSR, no atomics, bf16 lin input): one block per node (v13) ----------------
__global__ __launch_bounds__(64) void k_gather64(const short* __restrict__ hlin,
                                                 const int* __restrict__ offs,
                                                 const int* __restrict__ sSrc,
                                                 const float* __restrict__ dinv,
                                                 const void* __restrict__ bias,
                                                 const int* __restrict__ flag,
                                                 short* __restrict__ houtb) {
    int n = blockIdx.x;
    int c = threadIdx.x;
    int beg = offs[n], end = offs[n + 1];
    float di = dinv[n];
    float acc = 0.f;
    for (int j = beg; j < end; ++j) {
        int s = sSrc[j];
        acc += dinv[s] * bf2f(hlin[(long)s * 64 + c]);
    }
    float v = fmaxf(di * acc + di * di * bf2f(hlin[(long)n * 64 + c]) + ldf(bias, c, *flag), 0.f);
    houtb[(long)n * 64 + c] = f2bf(v);
}

__global__ __launch_bounds__(128) void k_gather128(const short* __restrict__ hlin,
                                                   const int* __restrict__ offs,
                                                   const int* __restrict__ sSrc,
                                                   const float* __restrict__ dinv,
                                                   const void* __restrict__ bias,
                                                   const int* __restrict__ flag,
                                                   short* __restrict__ h2b) {
    int n = blockIdx.x;
    int c = threadIdx.x;
    int beg = offs[n], end = offs[n + 1];
    float di = dinv[n];
    float acc = 0.f;
    for (int j = beg; j < end; ++j) {
        int s = sSrc[j];
        acc += dinv[s] * bf2f(hlin[(long)s * 128 + c]);
    }
    float v = fmaxf(di * acc + di * di * bf2f(hlin[(long)n * 128 + c]) + ldf(bias, c, *flag), 0.f);
    h2b[(long)n * 128 + c] = f2bf(v);
}

// ---------------- MFMA flash attention v16: v13-exact staging (CHUNK=64, 16KB LDS) ----------------
// Block = (head, q-block of 256 rows, K-split half). 8 waves each own 32 q-rows.
// Per 64-k chunk: 512 threads reg-stage K (4KB, waves 0-3) + V (4KB, waves 4-7) into
// swizzled LDS (issue-early / write-late), 2 sub-iters of the swapped-QK body from LDS.
// fp32 l accumulation. Measured: 65us, 0 bank conflicts, 32% occ, absmax 0.
__global__ __launch_bounds__(512) void k_attn_v16(const short* __restrict__ Qb,
                                                  const short* __restrict__ Kb,
                                                  const short* __restrict__ VTb,
                                                  short* __restrict__ po_base,
                                                  float* __restrict__ pl) {
    const int tid = threadIdx.x;
    const int lane = tid & 63;
    const int wid = tid >> 6;                    // wave 0..7
    const int m15 = lane & 15, quad = lane >> 4;
    const int b = blockIdx.x;
    const int mh = (b & 7) + 8 * (b >> 8);       // head, pinned to b%8 (XCD round-robin)
    const int mid = (b >> 3) & 31;
    const int z = mid & 1;                       // K-split half
    const int qb = mid >> 1;                     // q block (256 rows)
    const int q0 = qb * 256 + wid * 32;          // this wave's q tile
    const long hoff = (long)mh * 131072;
    const short* Qh = Qb + hoff;
    const short* Kh = Kb + hoff;
    const short* Vh = VTb + hoff;                // [32][4096], slot-permuted
    const int ks0 = z * 2048;

    __shared__ short Klds[2][2048];              // [64 k][32 d] linear, swzK on write+read
    __shared__ short Vlds[2][2048];              // [32 d][64 k] linear, swzV on write+read

    // per-thread staging addresses (K: waves 0-3, V: waves 4-7)
    int myOff, dstB;
    if (tid < 256) {
        int r = tid >> 2, part = tid & 3;
        myOff = r * 32 + part * 8;               // shorts within K chunk
        dstB  = swzK(r * 64 + part * 16);        // LDS byte
    } else {
        int u = tid - 256;
        int d = u >> 3, part = u & 7;
        myOff = d * 4096 + part * 8;             // shorts: V row base + k sub
        dstB  = swzV(d * 128 + part * 16);
    }

    // Q as B-operand fragments (rows q on lane&15)
    const bf16x8 qf0 = *(const bf16x8*)(Qh + (long)(q0 + m15) * 32 + quad * 8);
    const bf16x8 qf1 = *(const bf16x8*)(Qh + (long)(q0 + 16 + m15) * 32 + quad * 8);

    // fixed LDS read offsets (bytes) per 32-k sub-iter
    const int k00 = swzK((0 * 32 + m15) * 64 + quad * 16);
    const int k01 = swzK((0 * 32 + 16 + m15) * 64 + quad * 16);
    const int k10 = swzK((1 * 32 + m15) * 64 + quad * 16);
    const int k11 = swzK((1 * 32 + 16 + m15) * 64 + quad * 16);
    const int v00 = swzV(m15 * 128 + 0 * 64 + quad * 16);
    const int v01 = swzV((16 + m15) * 128 + 0 * 64 + quad * 16);
    const int v10 = swzV(m15 * 128 + 1 * 64 + quad * 16);
    const int v11 = swzV((16 + m15) * 128 + 1 * 64 + quad * 16);

    f32x4 oA0 = {0.f,0.f,0.f,0.f}, oA1 = {0.f,0.f,0.f,0.f};
    f32x4 oB0 = {0.f,0.f,0.f,0.f}, oB1 = {0.f,0.f,0.f,0.f};
    float lq0 = 0.f, lq1 = 0.f;

    // prologue: stage chunk 0
    int4 nx = (tid < 256) ? *(const int4*)(Kh + (long)ks0 * 32 + myOff)
                          : *(const int4*)(Vh + myOff + ks0);
    if (tid < 256) *(int4*)((char*)&Klds[0][0] + dstB) = nx;
    else           *(int4*)((char*)&Vlds[0][0] + dstB) = nx;
    __syncthreads();

    int cur = 0;
    for (int c = 0; c < NT; ++c) {
        const bool more = (c + 1 < NT);
        if (more) {
            int kc = ks0 + (c + 1) * CHUNK;
            nx = (tid < 256) ? *(const int4*)(Kh + (long)kc * 32 + myOff)
                             : *(const int4*)(Vh + myOff + kc);
        }
        const char* Kc = (const char*)&Klds[cur][0];
        const char* Vc = (const char*)&Vlds[cur][0];
#pragma unroll
        for (int s = 0; s < 2; ++s) {
            bf16x8 kf0 = *(const bf16x8*)(Kc + (s ? k10 : k00));
            bf16x8 kf1 = *(const bf16x8*)(Kc + (s ? k11 : k01));
            bf16x8 vf0 = *(const bf16x8*)(Vc + (s ? v10 : v00));
            bf16x8 vf1 = *(const bf16x8*)(Vc + (s ? v11 : v01));
            const f32x4 zz = {0.f,0.f,0.f,0.f};
            __builtin_amdgcn_s_setprio(1);
            f32x4 sA0 = __builtin_amdgcn_mfma_f32_16x16x32_bf16(kf0, qf0, zz, 0, 0, 0);
            f32x4 sA1 = __builtin_amdgcn_mfma_f32_16x16x32_bf16(kf1, qf0, zz, 0, 0, 0);
            f32x4 sB0 = __builtin_amdgcn_mfma_f32_16x16x32_bf16(kf0, qf1, zz, 0, 0, 0);
            f32x4 sB1 = __builtin_amdgcn_mfma_f32_16x16x32_bf16(kf1, qf1, zz, 0, 0, 0);
            __builtin_amdgcn_s_setprio(0);
            float pA0[4], pA1[4], pB0[4], pB1[4];
#pragma unroll
            for (int i = 0; i < 4; ++i) {
                pA0[i] = __builtin_amdgcn_exp2f(fminf(sA0[i], 100.f));
                pA1[i] = __builtin_amdgcn_exp2f(fminf(sA1[i], 100.f));
                pB0[i] = __builtin_amdgcn_exp2f(fminf(sB0[i], 100.f));
                pB1[i] = __builtin_amdgcn_exp2f(fminf(sB1[i], 100.f));
            }
            lq0 += (pA0[0] + pA0[1]) + (pA0[2] + pA0[3]) + (pA1[0] + pA1[1]) + (pA1[2] + pA1[3]);
            lq1 += (pB0[0] + pB0[1]) + (pB0[2] + pB0[3]) + (pB1[0] + pB1[1]) + (pB1[2] + pB1[3]);
            union { unsigned u[4]; bf16x8 v; } aq0, aq1;
            aq0.u[0] = __builtin_amdgcn_perm(__float_as_uint(pA0[1]), __float_as_uint(pA0[0]), 0x07060302u);
            aq0.u[1] = __builtin_amdgcn_perm(__float_as_uint(pA0[3]), __float_as_uint(pA0[2]), 0x07060302u);
            aq0.u[2] = __builtin_amdgcn_perm(__float_as_uint(pA1[1]), __float_as_uint(pA1[0]), 0x07060302u);
            aq0.u[3] = __builtin_amdgcn_perm(__float_as_uint(pA1[3]), __float_as_uint(pA1[2]), 0x07060302u);
            aq1.u[0] = __builtin_amdgcn_perm(__float_as_uint(pB0[1]), __float_as_uint(pB0[0]), 0x07060302u);
            aq1.u[1] = __builtin_amdgcn_perm(__float_as_uint(pB0[3]), __float_as_uint(pB0[2]), 0x07060302u);
            aq1.u[2] = __builtin_amdgcn_perm(__float_as_uint(pB1[1]), __float_as_uint(pB1[0]), 0x07060302u);
            aq1.u[3] = __builtin_amdgcn_perm(__float_as_uint(pB1[3]), __float_as_uint(pB1[2]), 0x07060302u);
            __builtin_amdgcn_s_setprio(1);
            oA0 = __builtin_amdgcn_mfma_f32_16x16x32_bf16(aq0.v, vf0, oA0, 0, 0, 0);
            oA1 = __builtin_amdgcn_mfma_f32_16x16x32_bf16(aq0.v, vf1, oA1, 0, 0, 0);
            oB0 = __builtin_amdgcn_mfma_f32_16x16x32_bf16(aq1.v, vf0, oB0, 0, 0, 0);
            oB1 = __builtin_amdgcn_mfma_f32_16x16x32_bf16(aq1.v, vf1, oB1, 0, 0, 0);
            __builtin_amdgcn_s_setprio(0);
        }
        if (more) {
            if (tid < 256) *(int4*)((char*)&Klds[cur ^ 1][0] + dstB) = nx;
            else           *(int4*)((char*)&Vlds[cur ^ 1][0] + dstB) = nx;
        }
        __syncthreads();
        cur ^= 1;
    }

    // row-sums spread across quads: reduce over lane bits 4,5
    lq0 += __shfl_xor(lq0, 16); lq0 += __shfl_xor(lq0, 32);
    lq1 += __shfl_xor(lq1, 16); lq1 += __shfl_xor(lq1, 32);

    short* po = po_base + (long)z * 2097152;
    const int base = (mh >> 2) * 128 + (mh & 3) * 32;
#pragma unroll
    for (int i = 0; i < 4; ++i) {
        int qa = q0 + quad * 4 + i;
        int qb2 = qa + 16;
        po[(long)qa * 512 + base + m15]       = f2bf(oA0[i]);
        po[(long)qa * 512 + base + 16 + m15]  = f2bf(oA1[i]);
        po[(long)qb2 * 512 + base + m15]      = f2bf(oB0[i]);
        po[(long)qb2 * 512 + base + 16 + m15] = f2bf(oB1[i]);
    }
    if (quad == 0) {
        pl[z * 65536 + mh * 4096 + q0 + m15] = lq0;
        pl[z * 65536 + mh * 4096 + q0 + 16 + m15] = lq1;
    }
}

// ---------------- combine + normalize partials once -> bf16 poN[4096][512] ----------------
__global__ __launch_bounds__(256) void k_norm(const short* __restrict__ po,
                                              const float* __restrict__ pl,
                                              short* __restrict__ poN) {
    int idx = blockIdx.x * 256 + threadIdx.x;    // octet index over [4096][64]
    int n = idx >> 6;
    int col = (idx & 63) * 8;
    int mh = ((col >> 7) << 2) | ((col >> 5) & 3);
    float l = pl[mh * 4096 + n] + pl[65536 + mh * 4096 + n];
    float inv = 1.f / fmaxf(l, 1e-30f);
    long base = (long)n * 512 + col;
    bf16x8 a0 = *(const bf16x8*)(po + base);
    bf16x8 a1 = *(const bf16x8*)(po + 2097152 + base);
    union { short s[8]; bf16x8 v; } r;
#pragma unroll
    for (int j = 0; j < 8; ++j)
        r.s[j] = f2bf((bf2f(a0[j]) + bf2f(a1[j])) * inv);
    *(bf16x8*)(poN + base) = r.v;
}

// ---------------- out-proj MFMA v2: B-panel in regs, 8 n-tiles/block -> fp32 hcat ----------------
// grid (8, 32, 4): hcat[n][m*128+c] = sum_k poN[n][m*128+k] * Wout[m][c][k] + bias
__global__ __launch_bounds__(64) void k_outproj(const short* __restrict__ poN,
                                                const short* __restrict__ Woutb,
                                                const void* __restrict__ bout,
                                                const int* __restrict__ flag,
                                                float* __restrict__ hcat) {
    const int lane = threadIdx.x;
    const int m15 = lane & 15, quad = lane >> 4;
    const int c0 = blockIdx.x * 16;
    const int m = blockIdx.z;

    // B-panel once (4 K-fragments of the 16 output cols of module m)
    bf16x8 bv0 = *(const bf16x8*)(Woutb + (long)(m * 128 + c0 + m15) * 128 +  0 + quad * 8);
    bf16x8 bv1 = *(const bf16x8*)(Woutb + (long)(m * 128 + c0 + m15) * 128 + 32 + quad * 8);
    bf16x8 bv2 = *(const bf16x8*)(Woutb + (long)(m * 128 + c0 + m15) * 128 + 64 + quad * 8);
    bf16x8 bv3 = *(const bf16x8*)(Woutb + (long)(m * 128 + c0 + m15) * 128 + 96 + quad * 8);
    const float bias = ldf(bout, m * 128 + c0 + m15, *flag);

#pragma unroll
    for (int t = 0; t < 8; ++t) {
        const int n0 = blockIdx.y * 128 + t * 16;
        f32x4 acc = {0.f,0.f,0.f,0.f};
        {
            bf16x8 a0 = *(const bf16x8*)(poN + (long)(n0 + m15) * 512 + m * 128 +  0 + quad * 8);
            acc = __builtin_amdgcn_mfma_f32_16x16x32_bf16(a0, bv0, acc, 0, 0, 0);
            bf16x8 a1 = *(const bf16x8*)(poN + (long)(n0 + m15) * 512 + m * 128 + 32 + quad * 8);
            acc = __builtin_amdgcn_mfma_f32_16x16x32_bf16(a1, bv1, acc, 0, 0, 0);
            bf16x8 a2 = *(const bf16x8*)(poN + (long)(n0 + m15) * 512 + m * 128 + 64 + quad * 8);
            acc = __builtin_amdgcn_mfma_f32_16x16x32_bf16(a2, bv2, acc, 0, 0, 0);
            bf16x8 a3 = *(const bf16x8*)(poN + (long)(n0 + m15) * 512 + m * 128 + 96 + quad * 8);
            acc = __builtin_amdgcn_mfma_f32_16x16x32_bf16(a3, bv3, acc, 0, 0, 0);
        }
#pragma unroll
        for (int i = 0; i < 4; ++i)
            hcat[(long)(n0 + quad * 4 + i) * 512 + m * 128 + c0 + m15] = acc[i] + bias;
    }
}

// ---------------- mean pool v3: node-parallel + LDS reduce ----------------
__global__ __launch_bounds__(1024) void k_pool3(const float* __restrict__ hcat,
                                                const int* __restrict__ starts,
                                                float* __restrict__ g) {
    int gr = blockIdx.x, cg = blockIdx.y;
    int tx = threadIdx.x, ty = threadIdx.y;
    int c = cg * 128 + tx;
    int beg = starts[gr], end = starts[gr + 1];
    float s = 0.f;
    for (int n = beg + ty; n < end; n += 8)
        s += hcat[(long)n * 512 + c];
    __shared__ float red[8][128];
    red[ty][tx] = s;
    __syncthreads();
    if (ty == 0) {
        float t = ((red[0][tx] + red[1][tx]) + (red[2][tx] + red[3][tx]))
                + ((red[4][tx] + red[5][tx]) + (red[6][tx] + red[7][tx]));
        int cnt = end - beg;
        g[gr * 512 + c] = t / (float)(cnt > 0 ? cnt : 1);
    }
}

// ---------------- MLP head: fp32 A, flag-aware W/bias (original tensors) ----------------
__global__ void k_gemm_mlp(const float* __restrict__ A, int lda,
                           const void* __restrict__ W,
                           const void* __restrict__ bias,
                           const int* __restrict__ flag,
                           float* __restrict__ C, int ldc,
                           int M, int N, int K, int relu) {
    const int wb = *flag;
    __shared__ float As[16][17];
    __shared__ float Ws[16][17];
    int tx = threadIdx.x, ty = threadIdx.y;
    int row = blockIdx.y * 16 + ty;
    int col = blockIdx.x * 16 + tx;
    float acc = 0.f;
    for (int k0 = 0; k0 < K; k0 += 16) {
        As[ty][tx] = (row < M && (k0 + tx) < K) ? A[(long)row * lda + k0 + tx] : 0.f;
        int wrow = blockIdx.x * 16 + ty;
        Ws[ty][tx] = (wrow < N && (k0 + tx) < K) ? ldf(W, (long)wrow * K + k0 + tx, wb) : 0.f;
        __syncthreads();
#pragma unroll
        for (int kk = 0; kk < 16; ++kk) acc += As[ty][kk] * Ws[tx][kk];
        __syncthreads();
    }
    if (row < M && col < N) {
        if (bias) acc += ldf(bias, col, wb);
        if (relu) acc = fmaxf(acc, 0.f);
        C[(long)row * ldc + col] = acc;
    }
}

// ---------------- log softmax over 10 classes, dtype-flagged output ----------------
__global__ void k_logsoftmax(const float* __restrict__ logits, const int* __restrict__ flag,
                             void* __restrict__ out) {
    int t = threadIdx.x;
    if (t >= N_GRAPHS) return;
    int isbf = *flag;
    float v[10];
    float mx = -1e30f;
    for (int c = 0; c < 10; ++c) { v[c] = logits[t * 10 + c]; mx = fmaxf(mx, v[c]); }
    float s = 0.f;
    for (int c = 0; c < 10; ++c) s += __expf(v[c] - mx);
    float lse = mx + __logf(s);
    for (int c = 0; c < 10; ++c) {
        float r = v[c] - lse;
        if (isbf) ((bf16*)out)[t * 10 + c] = (bf16)r;
        else      ((float*)out)[t * 10 + c] = r;
    }
}

extern "C" void kernel_launch(void* const* d_in, const int* in_sizes, int n_in,
                              void* d_out, int out_size, void* d_ws, size_t ws_size,
                              hipStream_t stream) {
    const void* x     = d_in[0];
    const int*  ei    = (const int*)d_in[1];
    const int*  batch = (const int*)d_in[2];
    const void* W1    = d_in[3];
    const void* b1    = d_in[4];
    const void* W2    = d_in[5];
    const void* b2    = d_in[6];
    const void* W_in  = d_in[7];
    const void* b_in  = d_in[8];
    const void* W_out = d_in[9];
    const void* b_out = d_in[10];
    const void* Wf1   = d_in[11];
    const void* bf1   = d_in[12];
    const void* Wf2   = d_in[13];
    const void* bf2   = d_in[14];

    const int* src = ei;
    const int* dst = ei + N_EDGES;

    // ---- workspace arena ----
    float* w = (float*)d_ws;
    size_t off = 0;
    auto alloc = [&](size_t n) { float* p = w + off; off += (n + 63) & ~(size_t)63; return p; };
    int*   flag   = (int*)alloc(64);
    float* dinv   = alloc(N_NODES);
    float* g      = alloc(N_GRAPHS * 512);
    float* hid    = alloc(N_GRAPHS * 256);
    float* logits = alloc(N_GRAPHS * 10);
    int*   degi   = (int*)alloc(N_NODES);
    int*   offs   = (int*)alloc(N_NODES + 64);
    int*   cursor = (int*)alloc(N_NODES);
    int*   sSrc   = (int*)alloc(N_EDGES);
    int*   starts = (int*)alloc(64);
    float* pl     = alloc(KSPL * 16 * N_NODES);     // K-split l partials
    float* xbf    = alloc(262144);   // 4096*128 shorts
    float* W1bf   = alloc(4096);     // 64*128 shorts
    float* W2bf   = alloc(4096);     // 128*64 shorts
    float* Winbf  = alloc(98304);    // 1536*128 shorts
    float* Woutbf = alloc(32768);    // 4*128*128 shorts
    float* h1linbf= alloc(131072);   // 4096*64 shorts
    float* h2linbf= alloc(262144);   // 4096*128 shorts
    float* h1bf   = alloc(131072);   // 4096*64 shorts
    float* h2bf   = alloc(262144);   // 4096*128 shorts
    float* pobf   = alloc((size_t)KSPL * 1048576);  // bf16 attention partials [z][4096][512]
    float* poNbf  = alloc(1048576);                 // normalized bf16 attention output
    float* hcat   = alloc(2097152);  // 4096*512 fp32
    float* bufQ   = alloc(3145728);  // Qb|Kb|VTb bf16 (12 MB)

    short* xb    = (short*)xbf;
    short* W1b   = (short*)W1bf;
    short* W2b   = (short*)W2bf;
    short* Winb  = (short*)Winbf;
    short* Woutb = (short*)Woutbf;
    short* h1lin = (short*)h1linbf;
    short* h2lin = (short*)h2linbf;
    short* h1b   = (short*)h1bf;
    short* h2b   = (short*)h2bf;
    short* po    = (short*)pobf;
    short* poN   = (short*)poNbf;
    short* Qb    = (short*)bufQ;
    short* Kb    = Qb + 2097152;
    short* VTb   = Qb + 4194304;

    dim3 b256(256);

    k_detect<<<dim3(1), dim3(64), 0, stream>>>(x, flag);

    // convert MFMA operand tensors to bf16 (flag-aware; bit-copy if already bf16)
    ConvSegs cs;
    cs.src0 = x;     cs.dst0 = xb;    cs.e0 = 524288;           // 4096*128
    cs.src1 = W1;    cs.dst1 = W1b;   cs.e1 = cs.e0 + 8192;     // 64*128
    cs.src2 = W2;    cs.dst2 = W2b;   cs.e2 = cs.e1 + 8192;     // 128*64
    cs.src3 = W_in;  cs.dst3 = Winb;  cs.e3 = cs.e2 + 196608;   // 1536*128
    cs.src4 = W_out; cs.dst4 = Woutb; cs.e4 = cs.e3 + 65536;    // 4*128*128
    k_tobf16<<<dim3((802816 + 255) / 256), b256, 0, stream>>>(cs, flag);

    hipMemsetAsync(degi, 0, N_NODES * sizeof(int), stream);
    k_deg<<<dim3((N_EDGES + 255) / 256), b256, 0, stream>>>(dst, degi);
    k_prep<<<dim3(1), dim3(1024), 0, stream>>>(degi, batch, offs, cursor, dinv, starts);
    k_sortedges<<<dim3((N_EDGES + 255) / 256), b256, 0, stream>>>(src, dst, cursor, sSrc);

    // GCN1: h1lin(bf16) = xb @ W1b^T (MFMA, B-reuse v2); gather -> h1b
    k_mfma_gemm_t<128><<<dim3(4, 32), dim3(64), 0, stream>>>(xb, W1b, h1lin, 64);
    k_gather64<<<dim3(N_NODES), dim3(64), 0, stream>>>(h1lin, offs, sSrc, dinv, b1, flag, h1b);

    // GCN2: h2lin(bf16) = h1b @ W2b^T (MFMA, B-reuse v2); gather -> h2b
    k_mfma_gemm_t<64><<<dim3(8, 32), dim3(64), 0, stream>>>(h1b, W2b, h2lin, 128);
    k_gather128<<<dim3(N_NODES), dim3(128), 0, stream>>>(h2lin, offs, sSrc, dinv, b2, flag, h2b);

    // fused qkv v2 (B-panel in regs, 8 n-tiles/block) -> Qb/Kb/VTb
    k_qkv<<<dim3(96, 32), dim3(64), 0, stream>>>(
        h2b, Winb, b_in, flag, Qb, Kb, VTb);

    // MFMA flash attention v16 (v13-exact staging: CHUNK=64, 16KB LDS, fp32 l)
    k_attn_v16<<<dim3(512), dim3(512), 0, stream>>>(Qb, Kb, VTb, po, pl);

    // combine+normalize once -> poN; out-proj v2 (B-reuse) -> fp32 hcat
    k_norm<<<dim3(1024), b256, 0, stream>>>(po, pl, poN);
    k_outproj<<<dim3(8, 32, 4), dim3(64), 0, stream>>>(
        poN, Woutb, b_out, flag, hcat);

    // mean pool (node-parallel v3) + MLP head + log-softmax
    k_pool3<<<dim3(N_GRAPHS, 4), dim3(128, 8), 0, stream>>>(hcat, starts, g);
    k_gemm_mlp<<<dim3(256 / 16, 1), dim3(16, 16), 0, stream>>>(
        g, 512, Wf1, bf1, flag, hid, 256, N_GRAPHS, 256, 512, 1);
    k_gemm_mlp<<<dim3(1, 1), dim3(16, 16), 0, stream>>>(
        hid, 256, Wf2, bf2, flag, logits, 10, N_GRAPHS, 10, 256, 0);
    k_logsoftmax<<<dim3(1), dim3(64), 0, stream>>>(logits, flag, d_out);
}

// Round 21
// 280.486 us; speedup vs baseline: 1.0375x; 1.0375x over previous
//
#include <hip/hip_runtime.h>
#include <hip/hip_bf16.h>

#define N_NODES 4096
#define N_EDGES 131072
#define N_GRAPHS 16
#define F_IN 128
#define D 128
#define QKVLD 1536   // 4 modules * 384
#define KSPL 2
#define CHUNK 64
#define NT (2048 / CHUNK)   // chunks per K-split half

typedef __hip_bfloat16 bf16;
typedef __attribute__((ext_vector_type(4))) float f32x4;
typedef __attribute__((ext_vector_type(8))) short bf16x8;

// float -> bf16 bits (RNE)
__device__ __forceinline__ short f2bf(float f) {
    unsigned u = __float_as_uint(f);
    unsigned r = (u + 0x7fffu + ((u >> 16) & 1u)) >> 16;
    return (short)r;
}
__device__ __forceinline__ float bf2f(short b) {
    return __uint_as_float(((unsigned)(unsigned short)b) << 16);
}
// Flagged load: isbf!=0 -> buffer holds bf16, else fp32. i is an ELEMENT index.
__device__ __forceinline__ float ldf(const void* p, long i, int isbf) {
    return isbf ? bf2f(((const short*)p)[i]) : ((const float*)p)[i];
}
// LDS bank swizzles (byte addrs, 16B-alignment preserved): v13-proven (0 conflicts)
__device__ __forceinline__ int swzK(int a) { return a ^ (((a >> 7) & 3) << 4); }
__device__ __forceinline__ int swzV(int a) { return a ^ (((a >> 7) & 7) << 4); }

// ---------------- dtype detector (bf16 data: all halfword exponents < 134) ----------------
__global__ void k_detect(const void* __restrict__ x, int* __restrict__ flag) {
    if (threadIdx.x == 0 && blockIdx.x == 0) {
        const unsigned short* h = (const unsigned short*)x;
        int bf = 1;
        for (int i = 0; i < 64; ++i) {
            int e = (h[i] >> 7) & 0xFF;
            if (e >= 134) { bf = 0; break; }
        }
        *flag = bf;
    }
}

// ---------------- flag-aware conversion of MFMA operand tensors to bf16 ----------------
struct ConvSegs {
    const void* src0; const void* src1; const void* src2; const void* src3; const void* src4;
    short* dst0; short* dst1; short* dst2; short* dst3; short* dst4;
    int e0, e1, e2, e3, e4;
};
__global__ void k_tobf16(ConvSegs s, const int* __restrict__ flag) {
    int idx = blockIdx.x * 256 + threadIdx.x;
    int isbf = *flag;
    const void* src; short* dst; int base;
    if (idx < s.e0)      { src = s.src0; dst = s.dst0; base = 0; }
    else if (idx < s.e1) { src = s.src1; dst = s.dst1; base = s.e0; }
    else if (idx < s.e2) { src = s.src2; dst = s.dst2; base = s.e1; }
    else if (idx < s.e3) { src = s.src3; dst = s.dst3; base = s.e2; }
    else if (idx < s.e4) { src = s.src4; dst = s.dst4; base = s.e3; }
    else return;
    int i = idx - base;
    dst[i] = f2bf(ldf(src, i, isbf));
}

__global__ void k_deg(const int* __restrict__ dst, int* __restrict__ degi) {
    int e = blockIdx.x * 256 + threadIdx.x;
    if (e < N_EDGES) atomicAdd(&degi[dst[e]], 1);
}

// ---------------- fused prep: degree scan + dinv + batch boundaries (one block) ----------------
__global__ __launch_bounds__(1024) void k_prep(const int* __restrict__ degi,
                                               const int* __restrict__ batch,
                                               int* __restrict__ offs,
                                               int* __restrict__ cursor,
                                               float* __restrict__ dinv,
                                               int* __restrict__ starts) {
    __shared__ int part[1024];
    int t = threadIdx.x;
    int4 v = *(const int4*)(degi + t * 4);
    int dv[4] = {v.x, v.y, v.z, v.w};
    int s = dv[0] + dv[1] + dv[2] + dv[3];
    part[t] = s;
    __syncthreads();
    for (int ofs = 1; ofs < 1024; ofs <<= 1) {
        int val = (t >= ofs) ? part[t - ofs] : 0;
        __syncthreads();
        part[t] += val;
        __syncthreads();
    }
    int o = part[t] - s;
#pragma unroll
    for (int j = 0; j < 4; ++j) {
        int n = t * 4 + j;
        offs[n] = o; cursor[n] = o;
        o += dv[j];
        dinv[n] = rsqrtf((float)(dv[j] + 1));   // +1 self loop
    }
    if (t == 1023) offs[4096] = o;
    // batch boundaries (batch is sorted)
#pragma unroll
    for (int j = 0; j < 4; ++j) {
        int n = t * 4 + j;
        int b = batch[n];
        if (n == 0) { for (int g2 = 0; g2 <= b; ++g2) starts[g2] = 0; }
        else {
            int pb = batch[n - 1];
            for (int g2 = pb + 1; g2 <= b; ++g2) starts[g2] = n;
        }
        if (n == N_NODES - 1) { for (int g2 = b + 1; g2 <= N_GRAPHS; ++g2) starts[g2] = N_NODES; }
    }
}

__global__ void k_sortedges(const int* __restrict__ src, const int* __restrict__ dst,
                            int* __restrict__ cursor, int* __restrict__ sSrc) {
    int e = blockIdx.x * 256 + threadIdx.x;
    if (e >= N_EDGES) return;
    int d = dst[e];
    int pos = atomicAdd(&cursor[d], 1);
    sSrc[pos] = src[e];
}

// ---------------- MFMA GEMM, bf16 out (no bias): C[M][ldc] bf16 = A @ W^T (r18 form) ----------------
__global__ __launch_bounds__(64) void k_mfma_gemm_s(const short* __restrict__ A, int lda,
                                                    const short* __restrict__ W,
                                                    short* __restrict__ C, int ldc, int K) {
    const int lane = threadIdx.x;
    const int m15 = lane & 15, quad = lane >> 4;
    const int c0 = blockIdx.x * 16;
    const int n0 = blockIdx.y * 16;
    f32x4 acc = {0.f, 0.f, 0.f, 0.f};
    for (int k0 = 0; k0 < K; k0 += 32) {
        bf16x8 a = *(const bf16x8*)(A + (long)(n0 + m15) * lda + k0 + quad * 8);
        bf16x8 b = *(const bf16x8*)(W + (long)(c0 + m15) * K + k0 + quad * 8);
        acc = __builtin_amdgcn_mfma_f32_16x16x32_bf16(a, b, acc, 0, 0, 0);
    }
#pragma unroll
    for (int i = 0; i < 4; ++i)
        C[(long)(n0 + quad * 4 + i) * ldc + c0 + m15] = f2bf(acc[i]);
}

// ---------------- fused qkv MFMA v2: B-panel in registers, 8 n-tiles per block ----------------
// grid (96, 32) = 3072 blocks (12 waves/CU — enough parallelism for B-reuse to pay).
// Measured win: total 293.1 -> 282.9 us vs 1-tile blocks.
__global__ __launch_bounds__(64) void k_qkv(const short* __restrict__ h2b,
                                            const short* __restrict__ Winb,
                                            const void* __restrict__ bin,
                                            const int* __restrict__ flag,
                                            short* __restrict__ Qb,
                                            short* __restrict__ Kb,
                                            short* __restrict__ VTb) {
    const int lane = threadIdx.x;
    const int m15 = lane & 15, quad = lane >> 4;
    const int c0 = blockIdx.x * 16;

    // B-panel once (4 K-fragments of the 16 output cols)
    bf16x8 bv0 = *(const bf16x8*)(Winb + (long)(c0 + m15) * 128 +  0 + quad * 8);
    bf16x8 bv1 = *(const bf16x8*)(Winb + (long)(c0 + m15) * 128 + 32 + quad * 8);
    bf16x8 bv2 = *(const bf16x8*)(Winb + (long)(c0 + m15) * 128 + 64 + quad * 8);
    bf16x8 bv3 = *(const bf16x8*)(Winb + (long)(c0 + m15) * 128 + 96 + quad * 8);

    // scatter-epilogue constants (n-independent), hoisted out of the n-loop
    const int c = c0 + m15;           // D layout: col = lane&15
    const int mmod = c / 384;
    const int r = c - mmod * 384;
    const int sect = r >> 7;          // 0=q, 1=k, 2=v (uniform per block)
    const int rr = r & 127;
    const int head = mmod * 4 + (rr >> 5);
    const int d = rr & 31;
    const float bias = ldf(bin, c, *flag);
    const float scale = 0.17677669529663687f * 1.4426950408889634f;  // 1/sqrt(32)*log2(e)

#pragma unroll
    for (int t = 0; t < 8; ++t) {
        const int n0 = blockIdx.y * 128 + t * 16;
        f32x4 acc = {0.f, 0.f, 0.f, 0.f};
        {
            bf16x8 a0 = *(const bf16x8*)(h2b + (long)(n0 + m15) * 128 +  0 + quad * 8);
            acc = __builtin_amdgcn_mfma_f32_16x16x32_bf16(a0, bv0, acc, 0, 0, 0);
            bf16x8 a1 = *(const bf16x8*)(h2b + (long)(n0 + m15) * 128 + 32 + quad * 8);
            acc = __builtin_amdgcn_mfma_f32_16x16x32_bf16(a1, bv1, acc, 0, 0, 0);
            bf16x8 a2 = *(const bf16x8*)(h2b + (long)(n0 + m15) * 128 + 64 + quad * 8);
            acc = __builtin_amdgcn_mfma_f32_16x16x32_bf16(a2, bv2, acc, 0, 0, 0);
            bf16x8 a3 = *(const bf16x8*)(h2b + (long)(n0 + m15) * 128 + 96 + quad * 8);
            acc = __builtin_amdgcn_mfma_f32_16x16x32_bf16(a3, bv3, acc, 0, 0, 0);
        }
        if (sect == 0) {
#pragma unroll
            for (int i = 0; i < 4; ++i)   // D layout: row = quad*4 + i
                Qb[(long)head * 131072 + (long)(n0 + quad * 4 + i) * 32 + d] = f2bf((acc[i] + bias) * scale);
        } else if (sect == 1) {
#pragma unroll
            for (int i = 0; i < 4; ++i)
                Kb[(long)head * 131072 + (long)(n0 + quad * 4 + i) * 32 + d] = f2bf(acc[i] + bias);
        } else {
            long vbase = (long)head * 131072 + (long)d * 4096;
#pragma unroll
            for (int i = 0; i < 4; ++i) {
                int n = n0 + quad * 4 + i;
                int phys = (n & ~31) | ((((n >> 2) & 3) << 3) | (((n >> 4) & 1) << 2) | (n & 3));
                VTb[vbase + phys] = f2bf(acc[i] + bias);
            }
        }
    }
}

// ---------------- GCN gather (CSR, no atomics, bf16 lin input): one block per node (v13) ----------------
__global__ __launch_bounds__(64) void k_gather64(const short* __restrict__ hlin,
                                                 const int* __restrict__ offs,
                                                 const int* __restrict__ sSrc,
                                                 const float* __restrict__ dinv,
                                                 const void* __restrict__ bias,
                                                 const int* __restrict__ flag,
                                                 short* __restrict__ houtb) {
    int n = blockIdx.x;
    int c = threadIdx.x;
    int beg = offs[n], end = offs[n + 1];
    float di = dinv[n];
    float acc = 0.f;
    for (int j = beg; j < end; ++j) {
        int s = sSrc[j];
        acc += dinv[s] * bf2f(hlin[(long)s * 64 + c]);
    }
    float v = fmaxf(di * acc + di * di * bf2f(hlin[(long)n * 64 + c]) + ldf(bias, c, *flag), 0.f);
    houtb[(long)n * 64 + c] = f2bf(v);
}

__global__ __launch_bounds__(128) void k_gather128(const short* __restrict__ hlin,
                                                   const int* __restrict__ offs,
                                                   const int* __restrict__ sSrc,
                                                   const float* __restrict__ dinv,
                                                   const void* __restrict__ bias,
                                                   const int* __restrict__ flag,
                                                   short* __restrict__ h2b) {
    int n = blockIdx.x;
    int c = threadIdx.x;
    int beg = offs[n], end = offs[n + 1];
    float di = dinv[n];
    float acc = 0.f;
    for (int j = beg; j < end; ++j) {
        int s = sSrc[j];
        acc += dinv[s] * bf2f(hlin[(long)s * 128 + c]);
    }
    float v = fmaxf(di * acc + di * di * bf2f(hlin[(long)n * 128 + c]) + ldf(bias, c, *flag), 0.f);
    h2b[(long)n * 128 + c] = f2bf(v);
}

// ---------------- MFMA flash attention v16: v13-exact staging (CHUNK=64, 16KB LDS) ----------------
// Block = (head, q-block of 256 rows, K-split half). 8 waves each own 32 q-rows.
// Per 64-k chunk: 512 threads reg-stage K (4KB, waves 0-3) + V (4KB, waves 4-7) into
// swizzled LDS (issue-early / write-late), 2 sub-iters of the swapped-QK body from LDS.
// fp32 l accumulation. Measured: 65us, 0 bank conflicts, 32% occ, absmax 0.
__global__ __launch_bounds__(512) void k_attn_v16(const short* __restrict__ Qb,
                                                  const short* __restrict__ Kb,
                                                  const short* __restrict__ VTb,
                                                  short* __restrict__ po_base,
                                                  float* __restrict__ pl) {
    const int tid = threadIdx.x;
    const int lane = tid & 63;
    const int wid = tid >> 6;                    // wave 0..7
    const int m15 = lane & 15, quad = lane >> 4;
    const int b = blockIdx.x;
    const int mh = (b & 7) + 8 * (b >> 8);       // head, pinned to b%8 (XCD round-robin)
    const int mid = (b >> 3) & 31;
    const int z = mid & 1;                       // K-split half
    const int qb = mid >> 1;                     // q block (256 rows)
    const int q0 = qb * 256 + wid * 32;          // this wave's q tile
    const long hoff = (long)mh * 131072;
    const short* Qh = Qb + hoff;
    const short* Kh = Kb + hoff;
    const short* Vh = VTb + hoff;                // [32][4096], slot-permuted
    const int ks0 = z * 2048;

    __shared__ short Klds[2][2048];              // [64 k][32 d] linear, swzK on write+read
    __shared__ short Vlds[2][2048];              // [32 d][64 k] linear, swzV on write+read

    // per-thread staging addresses (K: waves 0-3, V: waves 4-7)
    int myOff, dstB;
    if (tid < 256) {
        int r = tid >> 2, part = tid & 3;
        myOff = r * 32 + part * 8;               // shorts within K chunk
        dstB  = swzK(r * 64 + part * 16);        // LDS byte
    } else {
        int u = tid - 256;
        int d = u >> 3, part = u & 7;
        myOff = d * 4096 + part * 8;             // shorts: V row base + k sub
        dstB  = swzV(d * 128 + part * 16);
    }

    // Q as B-operand fragments (rows q on lane&15)
    const bf16x8 qf0 = *(const bf16x8*)(Qh + (long)(q0 + m15) * 32 + quad * 8);
    const bf16x8 qf1 = *(const bf16x8*)(Qh + (long)(q0 + 16 + m15) * 32 + quad * 8);

    // fixed LDS read offsets (bytes) per 32-k sub-iter
    const int k00 = swzK((0 * 32 + m15) * 64 + quad * 16);
    const int k01 = swzK((0 * 32 + 16 + m15) * 64 + quad * 16);
    const int k10 = swzK((1 * 32 + m15) * 64 + quad * 16);
    const int k11 = swzK((1 * 32 + 16 + m15) * 64 + quad * 16);
    const int v00 = swzV(m15 * 128 + 0 * 64 + quad * 16);
    const int v01 = swzV((16 + m15) * 128 + 0 * 64 + quad * 16);
    const int v10 = swzV(m15 * 128 + 1 * 64 + quad * 16);
    const int v11 = swzV((16 + m15) * 128 + 1 * 64 + quad * 16);

    f32x4 oA0 = {0.f,0.f,0.f,0.f}, oA1 = {0.f,0.f,0.f,0.f};
    f32x4 oB0 = {0.f,0.f,0.f,0.f}, oB1 = {0.f,0.f,0.f,0.f};
    float lq0 = 0.f, lq1 = 0.f;

    // prologue: stage chunk 0
    int4 nx = (tid < 256) ? *(const int4*)(Kh + (long)ks0 * 32 + myOff)
                          : *(const int4*)(Vh + myOff + ks0);
    if (tid < 256) *(int4*)((char*)&Klds[0][0] + dstB) = nx;
    else           *(int4*)((char*)&Vlds[0][0] + dstB) = nx;
    __syncthreads();

    int cur = 0;
    for (int c = 0; c < NT; ++c) {
        const bool more = (c + 1 < NT);
        if (more) {
            int kc = ks0 + (c + 1) * CHUNK;
            nx = (tid < 256) ? *(const int4*)(Kh + (long)kc * 32 + myOff)
                             : *(const int4*)(Vh + myOff + kc);
        }
        const char* Kc = (const char*)&Klds[cur][0];
        const char* Vc = (const char*)&Vlds[cur][0];
#pragma unroll
        for (int s = 0; s < 2; ++s) {
            bf16x8 kf0 = *(const bf16x8*)(Kc + (s ? k10 : k00));
            bf16x8 kf1 = *(const bf16x8*)(Kc + (s ? k11 : k01));
            bf16x8 vf0 = *(const bf16x8*)(Vc + (s ? v10 : v00));
            bf16x8 vf1 = *(const bf16x8*)(Vc + (s ? v11 : v01));
            const f32x4 zz = {0.f,0.f,0.f,0.f};
            __builtin_amdgcn_s_setprio(1);
            f32x4 sA0 = __builtin_amdgcn_mfma_f32_16x16x32_bf16(kf0, qf0, zz, 0, 0, 0);
            f32x4 sA1 = __builtin_amdgcn_mfma_f32_16x16x32_bf16(kf1, qf0, zz, 0, 0, 0);
            f32x4 sB0 = __builtin_amdgcn_mfma_f32_16x16x32_bf16(kf0, qf1, zz, 0, 0, 0);
            f32x4 sB1 = __builtin_amdgcn_mfma_f32_16x16x32_bf16(kf1, qf1, zz, 0, 0, 0);
            __builtin_amdgcn_s_setprio(0);
            float pA0[4], pA1[4], pB0[4], pB1[4];
#pragma unroll
            for (int i = 0; i < 4; ++i) {
                pA0[i] = __builtin_amdgcn_exp2f(fminf(sA0[i], 100.f));
                pA1[i] = __builtin_amdgcn_exp2f(fminf(sA1[i], 100.f));
                pB0[i] = __builtin_amdgcn_exp2f(fminf(sB0[i], 100.f));
                pB1[i] = __builtin_amdgcn_exp2f(fminf(sB1[i], 100.f));
            }
            lq0 += (pA0[0] + pA0[1]) + (pA0[2] + pA0[3]) + (pA1[0] + pA1[1]) + (pA1[2] + pA1[3]);
            lq1 += (pB0[0] + pB0[1]) + (pB0[2] + pB0[3]) + (pB1[0] + pB1[1]) + (pB1[2] + pB1[3]);
            union { unsigned u[4]; bf16x8 v; } aq0, aq1;
            aq0.u[0] = __builtin_amdgcn_perm(__float_as_uint(pA0[1]), __float_as_uint(pA0[0]), 0x07060302u);
            aq0.u[1] = __builtin_amdgcn_perm(__float_as_uint(pA0[3]), __float_as_uint(pA0[2]), 0x07060302u);
            aq0.u[2] = __builtin_amdgcn_perm(__float_as_uint(pA1[1]), __float_as_uint(pA1[0]), 0x07060302u);
            aq0.u[3] = __builtin_amdgcn_perm(__float_as_uint(pA1[3]), __float_as_uint(pA1[2]), 0x07060302u);
            aq1.u[0] = __builtin_amdgcn_perm(__float_as_uint(pB0[1]), __float_as_uint(pB0[0]), 0x07060302u);
            aq1.u[1] = __builtin_amdgcn_perm(__float_as_uint(pB0[3]), __float_as_uint(pB0[2]), 0x07060302u);
            aq1.u[2] = __builtin_amdgcn_perm(__float_as_uint(pB1[1]), __float_as_uint(pB1[0]), 0x07060302u);
            aq1.u[3] = __builtin_amdgcn_perm(__float_as_uint(pB1[3]), __float_as_uint(pB1[2]), 0x07060302u);
            __builtin_amdgcn_s_setprio(1);
            oA0 = __builtin_amdgcn_mfma_f32_16x16x32_bf16(aq0.v, vf0, oA0, 0, 0, 0);
            oA1 = __builtin_amdgcn_mfma_f32_16x16x32_bf16(aq0.v, vf1, oA1, 0, 0, 0);
            oB0 = __builtin_amdgcn_mfma_f32_16x16x32_bf16(aq1.v, vf0, oB0, 0, 0, 0);
            oB1 = __builtin_amdgcn_mfma_f32_16x16x32_bf16(aq1.v, vf1, oB1, 0, 0, 0);
            __builtin_amdgcn_s_setprio(0);
        }
        if (more) {
            if (tid < 256) *(int4*)((char*)&Klds[cur ^ 1][0] + dstB) = nx;
            else           *(int4*)((char*)&Vlds[cur ^ 1][0] + dstB) = nx;
        }
        __syncthreads();
        cur ^= 1;
    }

    // row-sums spread across quads: reduce over lane bits 4,5
    lq0 += __shfl_xor(lq0, 16); lq0 += __shfl_xor(lq0, 32);
    lq1 += __shfl_xor(lq1, 16); lq1 += __shfl_xor(lq1, 32);

    short* po = po_base + (long)z * 2097152;
    const int base = (mh >> 2) * 128 + (mh & 3) * 32;
#pragma unroll
    for (int i = 0; i < 4; ++i) {
        int qa = q0 + quad * 4 + i;
        int qb2 = qa + 16;
        po[(long)qa * 512 + base + m15]       = f2bf(oA0[i]);
        po[(long)qa * 512 + base + 16 + m15]  = f2bf(oA1[i]);
        po[(long)qb2 * 512 + base + m15]      = f2bf(oB0[i]);
        po[(long)qb2 * 512 + base + 16 + m15] = f2bf(oB1[i]);
    }
    if (quad == 0) {
        pl[z * 65536 + mh * 4096 + q0 + m15] = lq0;
        pl[z * 65536 + mh * 4096 + q0 + 16 + m15] = lq1;
    }
}

// ---------------- combine + normalize partials once -> bf16 poN[4096][512] ----------------
__global__ __launch_bounds__(256) void k_norm(const short* __restrict__ po,
                                              const float* __restrict__ pl,
                                              short* __restrict__ poN) {
    int idx = blockIdx.x * 256 + threadIdx.x;    // octet index over [4096][64]
    int n = idx >> 6;
    int col = (idx & 63) * 8;
    int mh = ((col >> 7) << 2) | ((col >> 5) & 3);
    float l = pl[mh * 4096 + n] + pl[65536 + mh * 4096 + n];
    float inv = 1.f / fmaxf(l, 1e-30f);
    long base = (long)n * 512 + col;
    bf16x8 a0 = *(const bf16x8*)(po + base);
    bf16x8 a1 = *(const bf16x8*)(po + 2097152 + base);
    union { short s[8]; bf16x8 v; } r;
#pragma unroll
    for (int j = 0; j < 8; ++j)
        r.s[j] = f2bf((bf2f(a0[j]) + bf2f(a1[j])) * inv);
    *(bf16x8*)(poN + base) = r.v;
}

// ---------------- out-proj MFMA v3: B-panel in regs, 2 n-tiles/block -> fp32 hcat ----------------
// grid (8, 128, 4) = 4096 blocks (16 waves/CU): keeps parallelism while halving B traffic.
__global__ __launch_bounds__(64) void k_outproj(const short* __restrict__ poN,
                                                const short* __restrict__ Woutb,
                                                const void* __restrict__ bout,
                                                const int* __restrict__ flag,
                                                float* __restrict__ hcat) {
    const int lane = threadIdx.x;
    const int m15 = lane & 15, quad = lane >> 4;
    const int c0 = blockIdx.x * 16;
    const int m = blockIdx.z;

    // B-panel once (4 K-fragments of the 16 output cols of module m)
    bf16x8 bv0 = *(const bf16x8*)(Woutb + (long)(m * 128 + c0 + m15) * 128 +  0 + quad * 8);
    bf16x8 bv1 = *(const bf16x8*)(Woutb + (long)(m * 128 + c0 + m15) * 128 + 32 + quad * 8);
    bf16x8 bv2 = *(const bf16x8*)(Woutb + (long)(m * 128 + c0 + m15) * 128 + 64 + quad * 8);
    bf16x8 bv3 = *(const bf16x8*)(Woutb + (long)(m * 128 + c0 + m15) * 128 + 96 + quad * 8);
    const float bias = ldf(bout, m * 128 + c0 + m15, *flag);

#pragma unroll
    for (int t = 0; t < 2; ++t) {
        const int n0 = blockIdx.y * 32 + t * 16;
        f32x4 acc = {0.f,0.f,0.f,0.f};
        {
            bf16x8 a0 = *(const bf16x8*)(poN + (long)(n0 + m15) * 512 + m * 128 +  0 + quad * 8);
            acc = __builtin_amdgcn_mfma_f32_16x16x32_bf16(a0, bv0, acc, 0, 0, 0);
            bf16x8 a1 = *(const bf16x8*)(poN + (long)(n0 + m15) * 512 + m * 128 + 32 + quad * 8);
            acc = __builtin_amdgcn_mfma_f32_16x16x32_bf16(a1, bv1, acc, 0, 0, 0);
            bf16x8 a2 = *(const bf16x8*)(poN + (long)(n0 + m15) * 512 + m * 128 + 64 + quad * 8);
            acc = __builtin_amdgcn_mfma_f32_16x16x32_bf16(a2, bv2, acc, 0, 0, 0);
            bf16x8 a3 = *(const bf16x8*)(poN + (long)(n0 + m15) * 512 + m * 128 + 96 + quad * 8);
            acc = __builtin_amdgcn_mfma_f32_16x16x32_bf16(a3, bv3, acc, 0, 0, 0);
        }
#pragma unroll
        for (int i = 0; i < 4; ++i)
            hcat[(long)(n0 + quad * 4 + i) * 512 + m * 128 + c0 + m15] = acc[i] + bias;
    }
}

// ---------------- mean pool v3: node-parallel + LDS reduce ----------------
__global__ __launch_bounds__(1024) void k_pool3(const float* __restrict__ hcat,
                                                const int* __restrict__ starts,
                                                float* __restrict__ g) {
    int gr = blockIdx.x, cg = blockIdx.y;
    int tx = threadIdx.x, ty = threadIdx.y;
    int c = cg * 128 + tx;
    int beg = starts[gr], end = starts[gr + 1];
    float s = 0.f;
    for (int n = beg + ty; n < end; n += 8)
        s += hcat[(long)n * 512 + c];
    __shared__ float red[8][128];
    red[ty][tx] = s;
    __syncthreads();
    if (ty == 0) {
        float t = ((red[0][tx] + red[1][tx]) + (red[2][tx] + red[3][tx]))
                + ((red[4][tx] + red[5][tx]) + (red[6][tx] + red[7][tx]));
        int cnt = end - beg;
        g[gr * 512 + c] = t / (float)(cnt > 0 ? cnt : 1);
    }
}

// ---------------- MLP head: fp32 A, flag-aware W/bias (original tensors) ----------------
__global__ void k_gemm_mlp(const float* __restrict__ A, int lda,
                           const void* __restrict__ W,
                           const void* __restrict__ bias,
                           const int* __restrict__ flag,
                           float* __restrict__ C, int ldc,
                           int M, int N, int K, int relu) {
    const int wb = *flag;
    __shared__ float As[16][17];
    __shared__ float Ws[16][17];
    int tx = threadIdx.x, ty = threadIdx.y;
    int row = blockIdx.y * 16 + ty;
    int col = blockIdx.x * 16 + tx;
    float acc = 0.f;
    for (int k0 = 0; k0 < K; k0 += 16) {
        As[ty][tx] = (row < M && (k0 + tx) < K) ? A[(long)row * lda + k0 + tx] : 0.f;
        int wrow = blockIdx.x * 16 + ty;
        Ws[ty][tx] = (wrow < N && (k0 + tx) < K) ? ldf(W, (long)wrow * K + k0 + tx, wb) : 0.f;
        __syncthreads();
#pragma unroll
        for (int kk = 0; kk < 16; ++kk) acc += As[ty][kk] * Ws[tx][kk];
        __syncthreads();
    }
    if (row < M && col < N) {
        if (bias) acc += ldf(bias, col, wb);
        if (relu) acc = fmaxf(acc, 0.f);
        C[(long)row * ldc + col] = acc;
    }
}

// ---------------- log softmax over 10 classes, dtype-flagged output ----------------
__global__ void k_logsoftmax(const float* __restrict__ logits, const int* __restrict__ flag,
                             void* __restrict__ out) {
    int t = threadIdx.x;
    if (t >= N_GRAPHS) return;
    int isbf = *flag;
    float v[10];
    float mx = -1e30f;
    for (int c = 0; c < 10; ++c) { v[c] = logits[t * 10 + c]; mx = fmaxf(mx, v[c]); }
    float s = 0.f;
    for (int c = 0; c < 10; ++c) s += __expf(v[c] - mx);
    float lse = mx + __logf(s);
    for (int c = 0; c < 10; ++c) {
        float r = v[c] - lse;
        if (isbf) ((bf16*)out)[t * 10 + c] = (bf16)r;
        else      ((float*)out)[t * 10 + c] = r;
    }
}

extern "C" void kernel_launch(void* const* d_in, const int* in_sizes, int n_in,
                              void* d_out, int out_size, void* d_ws, size_t ws_size,
                              hipStream_t stream) {
    const void* x     = d_in[0];
    const int*  ei    = (const int*)d_in[1];
    const int*  batch = (const int*)d_in[2];
    const void* W1    = d_in[3];
    const void* b1    = d_in[4];
    const void* W2    = d_in[5];
    const void* b2    = d_in[6];
    const void* W_in  = d_in[7];
    const void* b_in  = d_in[8];
    const void* W_out = d_in[9];
    const void* b_out = d_in[10];
    const void* Wf1   = d_in[11];
    const void* bf1   = d_in[12];
    const void* Wf2   = d_in[13];
    const void* bf2   = d_in[14];

    const int* src = ei;
    const int* dst = ei + N_EDGES;

    // ---- workspace arena ----
    float* w = (float*)d_ws;
    size_t off = 0;
    auto alloc = [&](size_t n) { float* p = w + off; off += (n + 63) & ~(size_t)63; return p; };
    int*   flag   = (int*)alloc(64);
    float* dinv   = alloc(N_NODES);
    float* g      = alloc(N_GRAPHS * 512);
    float* hid    = alloc(N_GRAPHS * 256);
    float* logits = alloc(N_GRAPHS * 10);
    int*   degi   = (int*)alloc(N_NODES);
    int*   offs   = (int*)alloc(N_NODES + 64);
    int*   cursor = (int*)alloc(N_NODES);
    int*   sSrc   = (int*)alloc(N_EDGES);
    int*   starts = (int*)alloc(64);
    float* pl     = alloc(KSPL * 16 * N_NODES);     // K-split l partials
    float* xbf    = alloc(262144);   // 4096*128 shorts
    float* W1bf   = alloc(4096);     // 64*128 shorts
    float* W2bf   = alloc(4096);     // 128*64 shorts
    float* Winbf  = alloc(98304);    // 1536*128 shorts
    float* Woutbf = alloc(32768);    // 4*128*128 shorts
    float* h1linbf= alloc(131072);   // 4096*64 shorts
    float* h2linbf= alloc(262144);   // 4096*128 shorts
    float* h1bf   = alloc(131072);   // 4096*64 shorts
    float* h2bf   = alloc(262144);   // 4096*128 shorts
    float* pobf   = alloc((size_t)KSPL * 1048576);  // bf16 attention partials [z][4096][512]
    float* poNbf  = alloc(1048576);                 // normalized bf16 attention output
    float* hcat   = alloc(2097152);  // 4096*512 fp32
    float* bufQ   = alloc(3145728);  // Qb|Kb|VTb bf16 (12 MB)

    short* xb    = (short*)xbf;
    short* W1b   = (short*)W1bf;
    short* W2b   = (short*)W2bf;
    short* Winb  = (short*)Winbf;
    short* Woutb = (short*)Woutbf;
    short* h1lin = (short*)h1linbf;
    short* h2lin = (short*)h2linbf;
    short* h1b   = (short*)h1bf;
    short* h2b   = (short*)h2bf;
    short* po    = (short*)pobf;
    short* poN   = (short*)poNbf;
    short* Qb    = (short*)bufQ;
    short* Kb    = Qb + 2097152;
    short* VTb   = Qb + 4194304;

    dim3 b256(256);

    k_detect<<<dim3(1), dim3(64), 0, stream>>>(x, flag);

    // convert MFMA operand tensors to bf16 (flag-aware; bit-copy if already bf16)
    ConvSegs cs;
    cs.src0 = x;     cs.dst0 = xb;    cs.e0 = 524288;           // 4096*128
    cs.src1 = W1;    cs.dst1 = W1b;   cs.e1 = cs.e0 + 8192;     // 64*128
    cs.src2 = W2;    cs.dst2 = W2b;   cs.e2 = cs.e1 + 8192;     // 128*64
    cs.src3 = W_in;  cs.dst3 = Winb;  cs.e3 = cs.e2 + 196608;   // 1536*128
    cs.src4 = W_out; cs.dst4 = Woutb; cs.e4 = cs.e3 + 65536;    // 4*128*128
    k_tobf16<<<dim3((802816 + 255) / 256), b256, 0, stream>>>(cs, flag);

    hipMemsetAsync(degi, 0, N_NODES * sizeof(int), stream);
    k_deg<<<dim3((N_EDGES + 255) / 256), b256, 0, stream>>>(dst, degi);
    k_prep<<<dim3(1), dim3(1024), 0, stream>>>(degi, batch, offs, cursor, dinv, starts);
    k_sortedges<<<dim3((N_EDGES + 255) / 256), b256, 0, stream>>>(src, dst, cursor, sSrc);

    // GCN1: h1lin(bf16) = xb @ W1b^T (MFMA); gather -> h1b
    k_mfma_gemm_s<<<dim3(4, N_NODES / 16), dim3(64), 0, stream>>>(
        xb, F_IN, W1b, h1lin, 64, F_IN);
    k_gather64<<<dim3(N_NODES), dim3(64), 0, stream>>>(h1lin, offs, sSrc, dinv, b1, flag, h1b);

    // GCN2: h2lin(bf16) = h1b @ W2b^T (MFMA); gather -> h2b
    k_mfma_gemm_s<<<dim3(8, N_NODES / 16), dim3(64), 0, stream>>>(
        h1b, 64, W2b, h2lin, 128, 64);
    k_gather128<<<dim3(N_NODES), dim3(128), 0, stream>>>(h2lin, offs, sSrc, dinv, b2, flag, h2b);

    // fused qkv v2 (B-panel in regs, 8 n-tiles/block) -> Qb/Kb/VTb
    k_qkv<<<dim3(96, 32), dim3(64), 0, stream>>>(
        h2b, Winb, b_in, flag, Qb, Kb, VTb);

    // MFMA flash attention v16 (v13-exact staging: CHUNK=64, 16KB LDS, fp32 l)
    k_attn_v16<<<dim3(512), dim3(512), 0, stream>>>(Qb, Kb, VTb, po, pl);

    // combine+normalize once -> poN; out-proj v3 (2-tile B-reuse, 4096 blocks) -> fp32 hcat
    k_norm<<<dim3(1024), b256, 0, stream>>>(po, pl, poN);
    k_outproj<<<dim3(8, 128, 4), dim3(64), 0, stream>>>(
        poN, Woutb, b_out, flag, hcat);

    // mean pool (node-parallel v3) + MLP head + log-softmax
    k_pool3<<<dim3(N_GRAPHS, 4), dim3(128, 8), 0, stream>>>(hcat, starts, g);
    k_gemm_mlp<<<dim3(256 / 16, 1), dim3(16, 16), 0, stream>>>(
        g, 512, Wf1, bf1, flag, hid, 256, N_GRAPHS, 256, 512, 1);
    k_gemm_mlp<<<dim3(1, 1), dim3(16, 16), 0, stream>>>(
        hid, 256, Wf2, bf2, flag, logits, 10, N_GRAPHS, 10, 256, 0);
    k_logsoftmax<<<dim3(1), dim3(64), 0, stream>>>(logits, flag, d_out);
}